// Round 1
// baseline (1129.251 us; speedup 1.0000x reference)
//
#include <hip/hip_runtime.h>
#include <stdint.h>

#define T_    100
#define B_    512
#define F_    784
#define H_    512
#define NOUT_ 10
#define R_    (T_*B_)      // 51200 rows
#define BH    (B_*H_)      // 262144

// ---------------------------------------------------------------------------
// GEMM0: CUR[r,n] = sum_k X[r,k]*W[n,k] + bias[n]    (M=51200, N=512, K=784)
// 128x128 tile, BK=16, 256 threads, 8x8 per thread (split 4+4 frags for
// conflict-free LDS reads: lanes stride 16B -> all 32 banks covered).
// ---------------------------------------------------------------------------
__global__ __launch_bounds__(256) void gemm0_kernel(
    const float* __restrict__ X, const float* __restrict__ W,
    const float* __restrict__ bias, float* __restrict__ C, int K)
{
    __shared__ float As[16][128];
    __shared__ float Bs[16][128];
    const int tid  = threadIdx.x;
    const int r0   = blockIdx.y * 128;
    const int n0   = blockIdx.x * 128;
    const int srow = tid >> 1;
    const int sk   = (tid & 1) * 8;
    const float* ag = X + (size_t)(r0 + srow) * K + sk;
    const float* bg = W + (size_t)(n0 + srow) * K + sk;
    const int ty = tid >> 4, tx = tid & 15;

    float acc[64];
#pragma unroll
    for (int i = 0; i < 64; i++) acc[i] = 0.f;

    for (int kt = 0; kt < K; kt += 16) {
        float4 av0 = *(const float4*)(ag + kt);
        float4 av1 = *(const float4*)(ag + kt + 4);
        float4 bv0 = *(const float4*)(bg + kt);
        float4 bv1 = *(const float4*)(bg + kt + 4);
        As[sk+0][srow]=av0.x; As[sk+1][srow]=av0.y; As[sk+2][srow]=av0.z; As[sk+3][srow]=av0.w;
        As[sk+4][srow]=av1.x; As[sk+5][srow]=av1.y; As[sk+6][srow]=av1.z; As[sk+7][srow]=av1.w;
        Bs[sk+0][srow]=bv0.x; Bs[sk+1][srow]=bv0.y; Bs[sk+2][srow]=bv0.z; Bs[sk+3][srow]=bv0.w;
        Bs[sk+4][srow]=bv1.x; Bs[sk+5][srow]=bv1.y; Bs[sk+6][srow]=bv1.z; Bs[sk+7][srow]=bv1.w;
        __syncthreads();
#pragma unroll
        for (int k = 0; k < 16; k++) {
            float a[8], b[8];
            *(float4*)&a[0] = *(const float4*)&As[k][ty*4];
            *(float4*)&a[4] = *(const float4*)&As[k][64 + ty*4];
            *(float4*)&b[0] = *(const float4*)&Bs[k][tx*4];
            *(float4*)&b[4] = *(const float4*)&Bs[k][64 + tx*4];
#pragma unroll
            for (int i = 0; i < 8; i++)
#pragma unroll
                for (int j = 0; j < 8; j++)
                    acc[i*8+j] = fmaf(a[i], b[j], acc[i*8+j]);
        }
        __syncthreads();
    }

    float bb[8];
    *(float4*)&bb[0] = *(const float4*)(bias + n0 + tx*4);
    *(float4*)&bb[4] = *(const float4*)(bias + n0 + 64 + tx*4);
#pragma unroll
    for (int i = 0; i < 8; i++) {
        int r = r0 + ((i >> 2) << 6) + ty*4 + (i & 3);
        float4 v0 = make_float4(acc[i*8+0]+bb[0], acc[i*8+1]+bb[1],
                                acc[i*8+2]+bb[2], acc[i*8+3]+bb[3]);
        float4 v1 = make_float4(acc[i*8+4]+bb[4], acc[i*8+5]+bb[5],
                                acc[i*8+6]+bb[6], acc[i*8+7]+bb[7]);
        *(float4*)(C + (size_t)r*512 + n0 + tx*4)      = v0;
        *(float4*)(C + (size_t)r*512 + n0 + 64 + tx*4) = v1;
    }
}

// ---------------------------------------------------------------------------
// GEMM1: CUR[r,n] = sum_f (Z[r,f]*alpha[t,f]+beta[t,f]) * W[n,f] + bias[n]
// t = r>>9 (constant per 128-row tile). Z is u8 spikes; affine applied while
// staging A into LDS. M=51200, N=512, K=512.
// ---------------------------------------------------------------------------
__global__ __launch_bounds__(256) void gemm1_kernel(
    const uint8_t* __restrict__ Z, const float* __restrict__ W,
    const float* __restrict__ bias, const float* __restrict__ alpha,
    const float* __restrict__ beta, float* __restrict__ C)
{
    const int K = 512;
    __shared__ float As[16][128];
    __shared__ float Bs[16][128];
    const int tid  = threadIdx.x;
    const int r0   = blockIdx.y * 128;
    const int n0   = blockIdx.x * 128;
    const int t    = r0 >> 9;
    const int srow = tid >> 1;
    const int sk   = (tid & 1) * 8;
    const uint8_t* ag = Z + (size_t)(r0 + srow) * K + sk;
    const float* bg  = W + (size_t)(n0 + srow) * K + sk;
    const float* alp = alpha + t*512 + sk;
    const float* bet = beta  + t*512 + sk;
    const int ty = tid >> 4, tx = tid & 15;

    float acc[64];
#pragma unroll
    for (int i = 0; i < 64; i++) acc[i] = 0.f;

    for (int kt = 0; kt < K; kt += 16) {
        uint32_t za = *(const uint32_t*)(ag + kt);
        uint32_t zb = *(const uint32_t*)(ag + kt + 4);
        float4 al0 = *(const float4*)(alp + kt);
        float4 al1 = *(const float4*)(alp + kt + 4);
        float4 be0 = *(const float4*)(bet + kt);
        float4 be1 = *(const float4*)(bet + kt + 4);
        float4 bv0 = *(const float4*)(bg + kt);
        float4 bv1 = *(const float4*)(bg + kt + 4);
        As[sk+0][srow] = fmaf((float)( za        & 0xffu), al0.x, be0.x);
        As[sk+1][srow] = fmaf((float)((za >> 8 ) & 0xffu), al0.y, be0.y);
        As[sk+2][srow] = fmaf((float)((za >> 16) & 0xffu), al0.z, be0.z);
        As[sk+3][srow] = fmaf((float)((za >> 24)        ), al0.w, be0.w);
        As[sk+4][srow] = fmaf((float)( zb        & 0xffu), al1.x, be1.x);
        As[sk+5][srow] = fmaf((float)((zb >> 8 ) & 0xffu), al1.y, be1.y);
        As[sk+6][srow] = fmaf((float)((zb >> 16) & 0xffu), al1.z, be1.z);
        As[sk+7][srow] = fmaf((float)((zb >> 24)        ), al1.w, be1.w);
        Bs[sk+0][srow]=bv0.x; Bs[sk+1][srow]=bv0.y; Bs[sk+2][srow]=bv0.z; Bs[sk+3][srow]=bv0.w;
        Bs[sk+4][srow]=bv1.x; Bs[sk+5][srow]=bv1.y; Bs[sk+6][srow]=bv1.z; Bs[sk+7][srow]=bv1.w;
        __syncthreads();
#pragma unroll
        for (int k = 0; k < 16; k++) {
            float a[8], b[8];
            *(float4*)&a[0] = *(const float4*)&As[k][ty*4];
            *(float4*)&a[4] = *(const float4*)&As[k][64 + ty*4];
            *(float4*)&b[0] = *(const float4*)&Bs[k][tx*4];
            *(float4*)&b[4] = *(const float4*)&Bs[k][64 + tx*4];
#pragma unroll
            for (int i = 0; i < 8; i++)
#pragma unroll
                for (int j = 0; j < 8; j++)
                    acc[i*8+j] = fmaf(a[i], b[j], acc[i*8+j]);
        }
        __syncthreads();
    }

    float bb[8];
    *(float4*)&bb[0] = *(const float4*)(bias + n0 + tx*4);
    *(float4*)&bb[4] = *(const float4*)(bias + n0 + 64 + tx*4);
#pragma unroll
    for (int i = 0; i < 8; i++) {
        int r = r0 + ((i >> 2) << 6) + ty*4 + (i & 3);
        float4 v0 = make_float4(acc[i*8+0]+bb[0], acc[i*8+1]+bb[1],
                                acc[i*8+2]+bb[2], acc[i*8+3]+bb[3]);
        float4 v1 = make_float4(acc[i*8+4]+bb[4], acc[i*8+5]+bb[5],
                                acc[i*8+6]+bb[6], acc[i*8+7]+bb[7]);
        *(float4*)(C + (size_t)r*512 + n0 + tx*4)      = v0;
        *(float4*)(C + (size_t)r*512 + n0 + 64 + tx*4) = v1;
    }
}

// ---------------------------------------------------------------------------
// LIF scan: per (b,h) element, iterate t=0..99.
//   v_dec = v + 0.1*(i - v); i_dec = 0.95*i; z = v_dec > 1; v' = (1-z)*v_dec;
//   i' = i_dec + cur.  Unfused rounding to match the reference exactly.
// ---------------------------------------------------------------------------
__global__ __launch_bounds__(256) void lif_kernel(
    const float* __restrict__ cur, uint8_t* __restrict__ z)
{
    const int tid = blockIdx.x * 256 + threadIdx.x;   // b*512 + h
    float v = 0.f, ii = 0.f;
    const float* p = cur + tid;
    uint8_t* q = z + tid;
    for (int t = 0; t < T_; t++) {
        float vd = __fadd_rn(v, __fmul_rn(0.1f, __fsub_rn(ii, v)));
        float id = __fmul_rn(ii, 0.95f);
        int zz = (vd > 1.0f) ? 1 : 0;
        v  = zz ? 0.f : vd;
        ii = __fadd_rn(id, p[(size_t)t * BH]);
        q[(size_t)t * BH] = (uint8_t)zz;
    }
}

// ---------------------------------------------------------------------------
// BN stats: spikes are binary -> mean m = s/512 (exact), var = m - m^2.
// alpha = g/sqrt(var+eps), beta = bt - m*alpha. One block per t, thread per h.
// ---------------------------------------------------------------------------
__global__ void bn_kernel(const uint8_t* __restrict__ z,
                          const float* __restrict__ g, const float* __restrict__ bt,
                          float* __restrict__ alpha, float* __restrict__ beta)
{
    const int t = blockIdx.x, h = threadIdx.x;
    const uint8_t* p = z + (size_t)t * BH + h;
    int s = 0;
    for (int b = 0; b < B_; b++) s += p[(size_t)b * H_];
    float m   = (float)s * (1.0f / 512.0f);
    float var = __fsub_rn(m, __fmul_rn(m, m));
    float al  = g[h] / sqrtf(__fadd_rn(var, 1e-5f));
    float be  = __fsub_rn(bt[h], __fmul_rn(m, al));
    alpha[t*H_ + h] = al;
    beta [t*H_ + h] = be;
}

// ---------------------------------------------------------------------------
// U[r,o] = sum_j (Z1[r,j]*a1[t,j]+b1[t,j]) * Wo[o,j].  One wave per row r;
// lane covers j = jj*64+lane. Wo (20KB) stays L1-hot across all blocks.
// ---------------------------------------------------------------------------
__global__ __launch_bounds__(256) void ugemm_kernel(
    const uint8_t* __restrict__ Z, const float* __restrict__ alpha,
    const float* __restrict__ beta, const float* __restrict__ Wo,
    float* __restrict__ U)
{
    const int tid  = threadIdx.x;
    const int wave = tid >> 6, lane = tid & 63;
    const size_t r = (size_t)blockIdx.x * 4 + wave;
    const int t = (int)(r >> 9);
    const uint8_t* zr = Z + r * 512;
    const float* alp = alpha + t*512;
    const float* bet = beta  + t*512;
    float acc[NOUT_];
#pragma unroll
    for (int o = 0; o < NOUT_; o++) acc[o] = 0.f;
#pragma unroll
    for (int jj = 0; jj < 8; jj++) {
        int j = jj*64 + lane;
        float h = fmaf((float)zr[j], alp[j], bet[j]);
#pragma unroll
        for (int o = 0; o < NOUT_; o++) acc[o] = fmaf(h, Wo[o*512 + j], acc[o]);
    }
#pragma unroll
    for (int o = 0; o < NOUT_; o++) {
        float v = acc[o];
#pragma unroll
        for (int off = 32; off; off >>= 1) v += __shfl_down(v, off, 64);
        if (lane == 0) U[r*NOUT_ + o] = v;
    }
}

// ---------------------------------------------------------------------------
// Output leaky-integrator scan per (b,o):
//   vo' = vo + 0.1*(io - vo);  out[t] = vo';  io' = 0.95*io + U[t]
// ---------------------------------------------------------------------------
__global__ void li_kernel(const float* __restrict__ U, float* __restrict__ out)
{
    const int tid = blockIdx.x * 256 + threadIdx.x;   // b*10 + o
    if (tid >= B_ * NOUT_) return;
    float vo = 0.f, io = 0.f;
    for (int t = 0; t < T_; t++) {
        vo = __fadd_rn(vo, __fmul_rn(0.1f, __fsub_rn(io, vo)));
        out[t*(B_*NOUT_) + tid] = vo;
        io = __fadd_rn(__fmul_rn(io, 0.95f), U[t*(B_*NOUT_) + tid]);
    }
}

// ---------------------------------------------------------------------------
extern "C" void kernel_launch(void* const* d_in, const int* in_sizes, int n_in,
                              void* d_out, int out_size, void* d_ws, size_t ws_size,
                              hipStream_t stream)
{
    const float* X   = (const float*)d_in[0];
    const float* W0  = (const float*)d_in[1];
    const float* b0  = (const float*)d_in[2];
    const float* W1  = (const float*)d_in[3];
    const float* b1  = (const float*)d_in[4];
    const float* g0  = (const float*)d_in[5];
    const float* bt0 = (const float*)d_in[6];
    const float* g1  = (const float*)d_in[7];
    const float* bt1 = (const float*)d_in[8];
    const float* Wo  = (const float*)d_in[9];
    float* out = (float*)d_out;

    // ws layout (total ~134 MB):
    //   CUR   : 51200*512 f32  = 104857600 B   (holds CUR0, then reused for CUR1)
    //   Zb    : 51200*512 u8   =  26214400 B   (holds Z0, then reused for Z1)
    //   a0,b0,a1,b1 : 100*512 f32 each
    //   U     : 51200*10 f32   =   2048000 B
    char* w = (char*)d_ws;
    float*   CUR    = (float*)w;
    uint8_t* Zb     = (uint8_t*)(w + 104857600);
    float*   alpha0 = (float*)(w + 104857600 + 26214400);
    float*   beta0  = alpha0 + R_;
    float*   alpha1 = beta0  + R_;
    float*   beta1  = alpha1 + R_;
    float*   U      = beta1  + R_;

    dim3 gg(4, 400);
    gemm0_kernel<<<gg,    256, 0, stream>>>(X, W0, b0, CUR, F_);
    lif_kernel  <<<1024,  256, 0, stream>>>(CUR, Zb);                 // -> Z0
    bn_kernel   <<<100,   512, 0, stream>>>(Zb, g0, bt0, alpha0, beta0);
    gemm1_kernel<<<gg,    256, 0, stream>>>(Zb, W1, b1, alpha0, beta0, CUR); // -> CUR1
    lif_kernel  <<<1024,  256, 0, stream>>>(CUR, Zb);                 // -> Z1
    bn_kernel   <<<100,   512, 0, stream>>>(Zb, g1, bt1, alpha1, beta1);
    ugemm_kernel<<<12800, 256, 0, stream>>>(Zb, alpha1, beta1, Wo, U);
    li_kernel   <<<20,    256, 0, stream>>>(U, out);
}

// Round 2
// 762.468 us; speedup vs baseline: 1.4810x; 1.4810x over previous
//
#include <hip/hip_runtime.h>
#include <stdint.h>

#define T_    100
#define B_    512
#define F_    784
#define FP_   800      // K for gemm0, zero-padded to a multiple of 32
#define H_    512
#define NOUT_ 10
#define R_    (T_*B_)      // 51200
#define BH    (B_*H_)      // 262144

typedef _Float16 f16x8 __attribute__((ext_vector_type(8)));
typedef _Float16 f16x4 __attribute__((ext_vector_type(4)));
typedef float    f32x4 __attribute__((ext_vector_type(4)));

__device__ __forceinline__ void gload_lds16(const void* g, void* l) {
    __builtin_amdgcn_global_load_lds(
        (const __attribute__((address_space(1))) uint32_t*)g,
        (__attribute__((address_space(3))) uint32_t*)l, 16, 0, 0);
}

// ---------------------------------------------------------------------------
// W -> fp16 hi/lo split, zero-padded to Kp columns.
// hi = RN16(w); lo = RN16(w - hi)  (w - hi exact in fp32 by Sterbenz)
// ---------------------------------------------------------------------------
__global__ void convW_kernel(const float* __restrict__ W, _Float16* __restrict__ Wh,
                             _Float16* __restrict__ Wl, int K, int Kp, int n)
{
    int idx = blockIdx.x * 256 + threadIdx.x;
    if (idx >= n) return;
    int r = idx / Kp, k = idx - r * Kp;
    float v = (k < K) ? W[r * K + k] : 0.f;
    _Float16 h = (_Float16)v;
    Wh[idx] = h;
    Wl[idx] = (_Float16)(v - (float)h);
}

// ---------------------------------------------------------------------------
// GEMM0: CUR[r,n] = sum_k X[r,k]*W0[n,k] + b0[n]   (M=51200,N=512,K=784->800)
// 128x128 tile, BK=32, 4 waves (2x2 of 64x64), fp16 hi/lo split, 3 MFMA/prod.
// B staged via global_load_lds (source pre-swizzled); A reg-staged fp32->hi/lo.
// LDS chunk swizzle: 16B chunk index ^= (row&3)  (both write & read sides).
// ---------------------------------------------------------------------------
__global__ __launch_bounds__(256) void gemm0_mfma(
    const float* __restrict__ X, const _Float16* __restrict__ Wh,
    const _Float16* __restrict__ Wl, const float* __restrict__ bias,
    float* __restrict__ C)
{
    __shared__ _Float16 Ah[128*32], Al[128*32], Bh[128*32], Bl[128*32];
    const int tid  = threadIdx.x;
    const int r0   = blockIdx.y * 128, n0 = blockIdx.x * 128;
    const int lane = tid & 63, wid = tid >> 6;
    const int wm = wid >> 1, wn = wid & 1;
    const int frow = lane & 15, fgrp = lane >> 4;

    const int brow0  = tid >> 2;         // B stage: + p*64
    const int bchunk = tid & 3;
    const int arow0  = tid >> 3;         // A stage: + q*32
    const int akk    = (tid & 7) * 4;
    const int achunk = akk >> 3;
    const int arem   = akk & 7;          // 0 or 4

    f32x4 acc[4][4];
#pragma unroll
    for (int i = 0; i < 4; i++)
#pragma unroll
        for (int j = 0; j < 4; j++) acc[i][j] = f32x4{0.f, 0.f, 0.f, 0.f};

    for (int kt = 0; kt < FP_; kt += 32) {
        __syncthreads();
#pragma unroll
        for (int p = 0; p < 2; p++) {
            int row  = p * 64 + brow0;
            int scol = kt + ((bchunk ^ (row & 3)) << 3);   // pre-swizzled source
            gload_lds16(Wh + (size_t)(n0 + row) * FP_ + scol, &Bh[p*2048 + tid*8]);
            gload_lds16(Wl + (size_t)(n0 + row) * FP_ + scol, &Bl[p*2048 + tid*8]);
        }
#pragma unroll
        for (int q = 0; q < 4; q++) {
            int row = q * 32 + arow0;
            float4 v;
            if (kt + akk < F_) v = *(const float4*)(X + (size_t)(r0 + row) * F_ + kt + akk);
            else               v = make_float4(0.f, 0.f, 0.f, 0.f);
            f16x4 hi, lo;
            hi[0] = (_Float16)v.x; lo[0] = (_Float16)(v.x - (float)hi[0]);
            hi[1] = (_Float16)v.y; lo[1] = (_Float16)(v.y - (float)hi[1]);
            hi[2] = (_Float16)v.z; lo[2] = (_Float16)(v.z - (float)hi[2]);
            hi[3] = (_Float16)v.w; lo[3] = (_Float16)(v.w - (float)hi[3]);
            int off = row * 32 + ((achunk ^ (row & 3)) << 3) + arem;
            *(f16x4*)&Ah[off] = hi;
            *(f16x4*)&Al[off] = lo;
        }
        __syncthreads();

        f16x8 ah[4], al[4], bh[4], bl[4];
#pragma unroll
        for (int mi = 0; mi < 4; mi++) {
            int row = wm * 64 + mi * 16 + frow;
            int off = row * 32 + ((fgrp ^ (row & 3)) << 3);
            ah[mi] = *(const f16x8*)&Ah[off];
            al[mi] = *(const f16x8*)&Al[off];
        }
#pragma unroll
        for (int ni = 0; ni < 4; ni++) {
            int row = wn * 64 + ni * 16 + frow;
            int off = row * 32 + ((fgrp ^ (row & 3)) << 3);
            bh[ni] = *(const f16x8*)&Bh[off];
            bl[ni] = *(const f16x8*)&Bl[off];
        }
#pragma unroll
        for (int mi = 0; mi < 4; mi++)
#pragma unroll
            for (int ni = 0; ni < 4; ni++) {
                acc[mi][ni] = __builtin_amdgcn_mfma_f32_16x16x32_f16(ah[mi], bh[ni], acc[mi][ni], 0, 0, 0);
                acc[mi][ni] = __builtin_amdgcn_mfma_f32_16x16x32_f16(ah[mi], bl[ni], acc[mi][ni], 0, 0, 0);
                acc[mi][ni] = __builtin_amdgcn_mfma_f32_16x16x32_f16(al[mi], bh[ni], acc[mi][ni], 0, 0, 0);
            }
    }

#pragma unroll
    for (int ni = 0; ni < 4; ni++) {
        int col = n0 + wn * 64 + ni * 16 + frow;
        float bv = bias[col];
#pragma unroll
        for (int mi = 0; mi < 4; mi++) {
            int rbase = r0 + wm * 64 + mi * 16 + fgrp * 4;
#pragma unroll
            for (int p = 0; p < 4; p++)
                C[(size_t)(rbase + p) * H_ + col] = acc[mi][ni][p] + bv;
        }
    }
}

// ---------------------------------------------------------------------------
// GEMM1: CUR[r,n] = sum_f (alpha[t,f]*Z[r,f]+beta[t,f])*W1[n,f] + b1[n]
// Same structure; A computed from u8 spikes + BN affine, split hi/lo in-flight.
// ---------------------------------------------------------------------------
__global__ __launch_bounds__(256) void gemm1_mfma(
    const uint8_t* __restrict__ Z, const _Float16* __restrict__ Wh,
    const _Float16* __restrict__ Wl, const float* __restrict__ bias,
    const float* __restrict__ alpha, const float* __restrict__ beta,
    float* __restrict__ C)
{
    __shared__ _Float16 Ah[128*32], Al[128*32], Bh[128*32], Bl[128*32];
    const int tid  = threadIdx.x;
    const int r0   = blockIdx.y * 128, n0 = blockIdx.x * 128;
    const int tt   = r0 >> 9;
    const int lane = tid & 63, wid = tid >> 6;
    const int wm = wid >> 1, wn = wid & 1;
    const int frow = lane & 15, fgrp = lane >> 4;

    const int brow0  = tid >> 2;
    const int bchunk = tid & 3;
    const int arow0  = tid >> 2;         // A stage: + q*64
    const int akk    = (tid & 3) * 8;
    const int achunk = tid & 3;

    f32x4 acc[4][4];
#pragma unroll
    for (int i = 0; i < 4; i++)
#pragma unroll
        for (int j = 0; j < 4; j++) acc[i][j] = f32x4{0.f, 0.f, 0.f, 0.f};

    for (int kt = 0; kt < H_; kt += 32) {
        __syncthreads();
#pragma unroll
        for (int p = 0; p < 2; p++) {
            int row  = p * 64 + brow0;
            int scol = kt + ((bchunk ^ (row & 3)) << 3);
            gload_lds16(Wh + (size_t)(n0 + row) * H_ + scol, &Bh[p*2048 + tid*8]);
            gload_lds16(Wl + (size_t)(n0 + row) * H_ + scol, &Bl[p*2048 + tid*8]);
        }
#pragma unroll
        for (int q = 0; q < 2; q++) {
            int row = q * 64 + arow0;
            uint2 zz = *(const uint2*)(Z + (size_t)(r0 + row) * H_ + kt + akk);
            float4 a0 = *(const float4*)(alpha + tt * H_ + kt + akk);
            float4 a1 = *(const float4*)(alpha + tt * H_ + kt + akk + 4);
            float4 e0 = *(const float4*)(beta  + tt * H_ + kt + akk);
            float4 e1 = *(const float4*)(beta  + tt * H_ + kt + akk + 4);
            float vl[8];
            vl[0] = fmaf((float)( zz.x        & 0xffu), a0.x, e0.x);
            vl[1] = fmaf((float)((zz.x >> 8 ) & 0xffu), a0.y, e0.y);
            vl[2] = fmaf((float)((zz.x >> 16) & 0xffu), a0.z, e0.z);
            vl[3] = fmaf((float)((zz.x >> 24)        ), a0.w, e0.w);
            vl[4] = fmaf((float)( zz.y        & 0xffu), a1.x, e1.x);
            vl[5] = fmaf((float)((zz.y >> 8 ) & 0xffu), a1.y, e1.y);
            vl[6] = fmaf((float)((zz.y >> 16) & 0xffu), a1.z, e1.z);
            vl[7] = fmaf((float)((zz.y >> 24)        ), a1.w, e1.w);
            f16x8 hi, lo;
#pragma unroll
            for (int j = 0; j < 8; j++) {
                hi[j] = (_Float16)vl[j];
                lo[j] = (_Float16)(vl[j] - (float)hi[j]);
            }
            int off = row * 32 + ((achunk ^ (row & 3)) << 3);
            *(f16x8*)&Ah[off] = hi;
            *(f16x8*)&Al[off] = lo;
        }
        __syncthreads();

        f16x8 ah[4], al[4], bh[4], bl[4];
#pragma unroll
        for (int mi = 0; mi < 4; mi++) {
            int row = wm * 64 + mi * 16 + frow;
            int off = row * 32 + ((fgrp ^ (row & 3)) << 3);
            ah[mi] = *(const f16x8*)&Ah[off];
            al[mi] = *(const f16x8*)&Al[off];
        }
#pragma unroll
        for (int ni = 0; ni < 4; ni++) {
            int row = wn * 64 + ni * 16 + frow;
            int off = row * 32 + ((fgrp ^ (row & 3)) << 3);
            bh[ni] = *(const f16x8*)&Bh[off];
            bl[ni] = *(const f16x8*)&Bl[off];
        }
#pragma unroll
        for (int mi = 0; mi < 4; mi++)
#pragma unroll
            for (int ni = 0; ni < 4; ni++) {
                acc[mi][ni] = __builtin_amdgcn_mfma_f32_16x16x32_f16(ah[mi], bh[ni], acc[mi][ni], 0, 0, 0);
                acc[mi][ni] = __builtin_amdgcn_mfma_f32_16x16x32_f16(ah[mi], bl[ni], acc[mi][ni], 0, 0, 0);
                acc[mi][ni] = __builtin_amdgcn_mfma_f32_16x16x32_f16(al[mi], bh[ni], acc[mi][ni], 0, 0, 0);
            }
    }

#pragma unroll
    for (int ni = 0; ni < 4; ni++) {
        int col = n0 + wn * 64 + ni * 16 + frow;
        float bv = bias[col];
#pragma unroll
        for (int mi = 0; mi < 4; mi++) {
            int rbase = r0 + wm * 64 + mi * 16 + fgrp * 4;
#pragma unroll
            for (int p = 0; p < 4; p++)
                C[(size_t)(rbase + p) * H_ + col] = acc[mi][ni][p] + bv;
        }
    }
}

// ---------------------------------------------------------------------------
// LIF scan (unchanged, verified round 1)
// ---------------------------------------------------------------------------
__global__ __launch_bounds__(256) void lif_kernel(
    const float* __restrict__ cur, uint8_t* __restrict__ z)
{
    const int tid = blockIdx.x * 256 + threadIdx.x;   // b*512 + h
    float v = 0.f, ii = 0.f;
    const float* p = cur + tid;
    uint8_t* q = z + tid;
    for (int t = 0; t < T_; t++) {
        float vd = __fadd_rn(v, __fmul_rn(0.1f, __fsub_rn(ii, v)));
        float id = __fmul_rn(ii, 0.95f);
        int zz = (vd > 1.0f) ? 1 : 0;
        v  = zz ? 0.f : vd;
        ii = __fadd_rn(id, p[(size_t)t * BH]);
        q[(size_t)t * BH] = (uint8_t)zz;
    }
}

// ---------------------------------------------------------------------------
// BN stats (unchanged, verified round 1)
// ---------------------------------------------------------------------------
__global__ void bn_kernel(const uint8_t* __restrict__ z,
                          const float* __restrict__ g, const float* __restrict__ bt,
                          float* __restrict__ alpha, float* __restrict__ beta)
{
    const int t = blockIdx.x, h = threadIdx.x;
    const uint8_t* p = z + (size_t)t * BH + h;
    int s = 0;
    for (int b = 0; b < B_; b++) s += p[(size_t)b * H_];
    float m   = (float)s * (1.0f / 512.0f);
    float var = __fsub_rn(m, __fmul_rn(m, m));
    float al  = g[h] / sqrtf(__fadd_rn(var, 1e-5f));
    float be  = __fsub_rn(bt[h], __fmul_rn(m, al));
    alpha[t*H_ + h] = al;
    beta [t*H_ + h] = be;
}

// ---------------------------------------------------------------------------
// U = h1 @ Wo^T (unchanged, verified round 1)
// ---------------------------------------------------------------------------
__global__ __launch_bounds__(256) void ugemm_kernel(
    const uint8_t* __restrict__ Z, const float* __restrict__ alpha,
    const float* __restrict__ beta, const float* __restrict__ Wo,
    float* __restrict__ U)
{
    const int tid  = threadIdx.x;
    const int wave = tid >> 6, lane = tid & 63;
    const size_t r = (size_t)blockIdx.x * 4 + wave;
    const int t = (int)(r >> 9);
    const uint8_t* zr = Z + r * 512;
    const float* alp = alpha + t*512;
    const float* bet = beta  + t*512;
    float acc[NOUT_];
#pragma unroll
    for (int o = 0; o < NOUT_; o++) acc[o] = 0.f;
#pragma unroll
    for (int jj = 0; jj < 8; jj++) {
        int j = jj*64 + lane;
        float h = fmaf((float)zr[j], alp[j], bet[j]);
#pragma unroll
        for (int o = 0; o < NOUT_; o++) acc[o] = fmaf(h, Wo[o*512 + j], acc[o]);
    }
#pragma unroll
    for (int o = 0; o < NOUT_; o++) {
        float v = acc[o];
#pragma unroll
        for (int off = 32; off; off >>= 1) v += __shfl_down(v, off, 64);
        if (lane == 0) U[r*NOUT_ + o] = v;
    }
}

// ---------------------------------------------------------------------------
// Output leaky integrator (unchanged, verified round 1)
// ---------------------------------------------------------------------------
__global__ void li_kernel(const float* __restrict__ U, float* __restrict__ out)
{
    const int tid = blockIdx.x * 256 + threadIdx.x;   // b*10 + o
    if (tid >= B_ * NOUT_) return;
    float vo = 0.f, io = 0.f;
    for (int t = 0; t < T_; t++) {
        vo = __fadd_rn(vo, __fmul_rn(0.1f, __fsub_rn(io, vo)));
        out[t*(B_*NOUT_) + tid] = vo;
        io = __fadd_rn(__fmul_rn(io, 0.95f), U[t*(B_*NOUT_) + tid]);
    }
}

// ---------------------------------------------------------------------------
extern "C" void kernel_launch(void* const* d_in, const int* in_sizes, int n_in,
                              void* d_out, int out_size, void* d_ws, size_t ws_size,
                              hipStream_t stream)
{
    const float* X   = (const float*)d_in[0];
    const float* W0  = (const float*)d_in[1];
    const float* b0  = (const float*)d_in[2];
    const float* W1  = (const float*)d_in[3];
    const float* b1  = (const float*)d_in[4];
    const float* g0  = (const float*)d_in[5];
    const float* bt0 = (const float*)d_in[6];
    const float* g1  = (const float*)d_in[7];
    const float* bt1 = (const float*)d_in[8];
    const float* Wo  = (const float*)d_in[9];
    float* out = (float*)d_out;

    // ws layout (~137 MB): CUR | Zb | alpha0,beta0,alpha1,beta1 | U | W0h,W0l,W1h,W1l
    char* w = (char*)d_ws;
    float*    CUR    = (float*)w;                         // 104857600 B
    uint8_t*  Zb     = (uint8_t*)(w + 104857600);         //  26214400 B
    float*    alpha0 = (float*)(w + 104857600 + 26214400);
    float*    beta0  = alpha0 + T_*H_;
    float*    alpha1 = beta0  + T_*H_;
    float*    beta1  = alpha1 + T_*H_;
    float*    U      = beta1  + T_*H_;                    // 2048000 B
    _Float16* W0h    = (_Float16*)(U + R_*NOUT_);         // 819200 B
    _Float16* W0l    = W0h + 512*FP_;
    _Float16* W1h    = W0l + 512*FP_;                     // 524288 B
    _Float16* W1l    = W1h + 512*H_;

    convW_kernel<<<(512*FP_+255)/256, 256, 0, stream>>>(W0, W0h, W0l, F_, FP_, 512*FP_);
    convW_kernel<<<(512*H_ +255)/256, 256, 0, stream>>>(W1, W1h, W1l, H_, H_,  512*H_);

    dim3 gg(4, 400);
    gemm0_mfma <<<gg,    256, 0, stream>>>(X, W0h, W0l, b0, CUR);
    lif_kernel <<<1024,  256, 0, stream>>>(CUR, Zb);                    // -> Z0
    bn_kernel  <<<100,   512, 0, stream>>>(Zb, g0, bt0, alpha0, beta0);
    gemm1_mfma <<<gg,    256, 0, stream>>>(Zb, W1h, W1l, b1, alpha0, beta0, CUR);
    lif_kernel <<<1024,  256, 0, stream>>>(CUR, Zb);                    // -> Z1
    bn_kernel  <<<100,   512, 0, stream>>>(Zb, g1, bt1, alpha1, beta1);
    ugemm_kernel<<<12800,256, 0, stream>>>(Zb, alpha1, beta1, Wo, U);
    li_kernel  <<<20,    256, 0, stream>>>(U, out);
}

// Round 3
// 605.038 us; speedup vs baseline: 1.8664x; 1.2602x over previous
//
#include <hip/hip_runtime.h>
#include <stdint.h>

#define T_    100
#define B_    512
#define F_    784
#define FP_   800      // K for gemm0, zero-padded to a multiple of 32
#define H_    512
#define NOUT_ 10
#define R_    (T_*B_)      // 51200
#define BH    (B_*H_)      // 262144

typedef _Float16 f16x8 __attribute__((ext_vector_type(8)));
typedef float    f32x4 __attribute__((ext_vector_type(4)));

__device__ __forceinline__ void gload_lds16(const void* g, void* l) {
    __builtin_amdgcn_global_load_lds(
        (const __attribute__((address_space(1))) uint32_t*)g,
        (__attribute__((address_space(3))) uint32_t*)l, 16, 0, 0);
}

// ---------------------------------------------------------------------------
// W0 -> fp16 hi/lo split, zero-padded to Kp columns.
// ---------------------------------------------------------------------------
__global__ void convW_kernel(const float* __restrict__ W, _Float16* __restrict__ Wh,
                             _Float16* __restrict__ Wl, int K, int Kp, int n)
{
    int idx = blockIdx.x * 256 + threadIdx.x;
    if (idx >= n) return;
    int r = idx / Kp, k = idx - r * Kp;
    float v = (k < K) ? W[r * K + k] : 0.f;
    _Float16 h = (_Float16)v;
    Wh[idx] = h;
    Wl[idx] = (_Float16)(v - (float)h);
}

// ---------------------------------------------------------------------------
// GEMM0: CUR[r,n] = sum_k X[r,k]*W0[n,k] + b0[n]   (M=51200,N=512,K=784->800)
// 128x128 tile, BK=32, 2-phase double-buffered: issue stage(t+1) -> ds_read
// frags(t) -> 48 MFMA -> convert+ds_write A(t+1) -> barrier.
// Swizzle: 16B chunk ^= (row>>1)&3  (8 slots / 8 rows -> 2-way = free).
// XCD-chunked block swizzle: the 4 N-blocks of an M-panel share one XCD L2.
// ---------------------------------------------------------------------------
__global__ __launch_bounds__(256, 2) void gemm0_mfma(
    const float* __restrict__ X, const _Float16* __restrict__ Wh,
    const _Float16* __restrict__ Wl, const float* __restrict__ bias,
    float* __restrict__ C)
{
    __shared__ _Float16 L[2 * 4 * 4096];   // [buf][Ah,Al,Bh,Bl][128*32]
    const int tid  = threadIdx.x;
    const int gl   = (blockIdx.x & 7) * 200 + (blockIdx.x >> 3);  // 1600 = 8*200
    const int r0   = (gl >> 2) * 128;
    const int n0   = (gl & 3) * 128;
    const int lane = tid & 63;
    const int wm = (tid >> 7) & 1, wn = (tid >> 6) & 1;
    const int frow = lane & 15, fgrp = lane >> 4;

    // B staging via gload_lds: slots tid (rows 0..63) and tid+256 (rows 64..127)
    const int brow = tid >> 2;
    const int bcol = (((tid & 3) ^ ((brow >> 1) & 3)) << 3);  // swz(row+64)==swz(row)
    const _Float16* WhB = Wh + (size_t)(n0 + brow) * FP_ + bcol;
    const _Float16* WlB = Wl + (size_t)(n0 + brow) * FP_ + bcol;

    // A staging (reg): row = tid>>1, 16 cols at half*16
    const int arow = tid >> 1, ahalf = tid & 1;
    const float* Xb = X + (size_t)(r0 + arow) * F_ + ahalf * 16;
    const int aoff = arow * 32;
    const int ac0  = (((ahalf * 2)     ^ ((arow >> 1) & 3)) << 3);
    const int ac1  = (((ahalf * 2 + 1) ^ ((arow >> 1) & 3)) << 3);

    f32x4 acc[4][4];
#pragma unroll
    for (int i = 0; i < 4; i++)
#pragma unroll
        for (int j = 0; j < 4; j++) acc[i][j] = f32x4{0.f, 0.f, 0.f, 0.f};

    auto stageB = [&](int buf, int kt) {
        _Float16* dh = L + buf * 16384 + 8192;
        _Float16* dl = L + buf * 16384 + 12288;
        gload_lds16(WhB + kt,            dh + tid * 8);
        gload_lds16(WhB + 64 * FP_ + kt, dh + 2048 + tid * 8);
        gload_lds16(WlB + kt,            dl + tid * 8);
        gload_lds16(WlB + 64 * FP_ + kt, dl + 2048 + tid * 8);
    };
    auto loadA = [&](float4* xa, int kt) {
#pragma unroll
        for (int j = 0; j < 4; j++) {
            int c = kt + ahalf * 16 + j * 4;
            xa[j] = (c < F_) ? *(const float4*)(Xb + kt + j * 4)
                             : make_float4(0.f, 0.f, 0.f, 0.f);
        }
    };
    auto writeA = [&](const float4* xa, int buf) {
        _Float16* dh = L + buf * 16384;
        _Float16* dl = L + buf * 16384 + 4096;
        const float* v = (const float*)xa;
        f16x8 h0, l0, h1, l1;
#pragma unroll
        for (int j = 0; j < 8; j++) {
            _Float16 a = (_Float16)v[j];
            h0[j] = a; l0[j] = (_Float16)(v[j] - (float)a);
            _Float16 b = (_Float16)v[8 + j];
            h1[j] = b; l1[j] = (_Float16)(v[8 + j] - (float)b);
        }
        *(f16x8*)(dh + aoff + ac0) = h0;
        *(f16x8*)(dh + aoff + ac1) = h1;
        *(f16x8*)(dl + aoff + ac0) = l0;
        *(f16x8*)(dl + aoff + ac1) = l1;
    };

    {   // prologue: stage kt=0 into buf0
        stageB(0, 0);
        float4 xa[4];
        loadA(xa, 0);
        writeA(xa, 0);
    }
    __syncthreads();

    int cur = 0;
    for (int kt = 0; kt < FP_; kt += 32) {
        const int nxt = cur ^ 1;
        const bool has = (kt + 32) < FP_;
        float4 xa[4];
        if (has) { stageB(nxt, kt + 32); loadA(xa, kt + 32); }

        const _Float16* bp = L + cur * 16384;
        f16x8 ah[4], al[4], bh[4], bl[4];
#pragma unroll
        for (int mi = 0; mi < 4; mi++) {
            int row = wm * 64 + mi * 16 + frow;
            int off = row * 32 + ((fgrp ^ ((row >> 1) & 3)) << 3);
            ah[mi] = *(const f16x8*)(bp + off);
            al[mi] = *(const f16x8*)(bp + 4096 + off);
        }
#pragma unroll
        for (int ni = 0; ni < 4; ni++) {
            int row = wn * 64 + ni * 16 + frow;
            int off = row * 32 + ((fgrp ^ ((row >> 1) & 3)) << 3);
            bh[ni] = *(const f16x8*)(bp + 8192 + off);
            bl[ni] = *(const f16x8*)(bp + 12288 + off);
        }
#pragma unroll
        for (int mi = 0; mi < 4; mi++)
#pragma unroll
            for (int ni = 0; ni < 4; ni++) {
                acc[mi][ni] = __builtin_amdgcn_mfma_f32_16x16x32_f16(ah[mi], bh[ni], acc[mi][ni], 0, 0, 0);
                acc[mi][ni] = __builtin_amdgcn_mfma_f32_16x16x32_f16(ah[mi], bl[ni], acc[mi][ni], 0, 0, 0);
                acc[mi][ni] = __builtin_amdgcn_mfma_f32_16x16x32_f16(al[mi], bh[ni], acc[mi][ni], 0, 0, 0);
            }

        if (has) writeA(xa, nxt);
        __syncthreads();
        cur = nxt;
    }

#pragma unroll
    for (int ni = 0; ni < 4; ni++) {
        int col = n0 + wn * 64 + ni * 16 + frow;
        float bv = bias[col];
#pragma unroll
        for (int mi = 0; mi < 4; mi++) {
            int rbase = r0 + wm * 64 + mi * 16 + fgrp * 4;
#pragma unroll
            for (int p = 0; p < 4; p++)
                C[(size_t)(rbase + p) * H_ + col] = acc[mi][ni][p] + bv;
        }
    }
}

// ---------------------------------------------------------------------------
// GEMM1: CUR[r,n] = sum_f Z[r,f] * (alpha[t,f]*W1[n,f]) + bW[t,n]
// A = spikes in fp16 (EXACT) via gload_lds -> only 2 MFMAs per product.
// B = alpha-folded W1, computed fp32 + hi/lo split during staging.
// bW[t,n] = beta@W1^T + b1 precomputed (bw_kernel).
// ---------------------------------------------------------------------------
__global__ __launch_bounds__(256, 3) void gemm1_mfma(
    const _Float16* __restrict__ Zh, const float* __restrict__ W1,
    const float* __restrict__ alpha, const float* __restrict__ bW,
    float* __restrict__ C)
{
    __shared__ _Float16 L[2 * 3 * 4096];   // [buf][Az,Bh,Bl][128*32]
    const int tid  = threadIdx.x;
    const int gl   = (blockIdx.x & 7) * 200 + (blockIdx.x >> 3);
    const int r0   = (gl >> 2) * 128;
    const int n0   = (gl & 3) * 128;
    const int tt   = r0 >> 9;
    const int lane = tid & 63;
    const int wm = (tid >> 7) & 1, wn = (tid >> 6) & 1;
    const int frow = lane & 15, fgrp = lane >> 4;

    // A staging via gload_lds
    const int arow = tid >> 2;
    const int acol = (((tid & 3) ^ ((arow >> 1) & 3)) << 3);
    const _Float16* ZhB = Zh + (size_t)(r0 + arow) * H_ + acol;

    // B staging (reg + alpha fold): row = tid>>1, half = tid&1
    const int brow = tid >> 1, bhalf = tid & 1;
    const float* W1B = W1 + (size_t)(n0 + brow) * H_ + bhalf * 16;
    const float* alB = alpha + tt * H_ + bhalf * 16;
    const int boff = brow * 32;
    const int bc0  = (((bhalf * 2)     ^ ((brow >> 1) & 3)) << 3);
    const int bc1  = (((bhalf * 2 + 1) ^ ((brow >> 1) & 3)) << 3);

    f32x4 acc[4][4];
#pragma unroll
    for (int i = 0; i < 4; i++)
#pragma unroll
        for (int j = 0; j < 4; j++) acc[i][j] = f32x4{0.f, 0.f, 0.f, 0.f};

    auto stageA = [&](int buf, int kt) {
        _Float16* d = L + buf * 12288;
        gload_lds16(ZhB + kt,           d + tid * 8);
        gload_lds16(ZhB + 64 * H_ + kt, d + 2048 + tid * 8);
    };
    auto loadB = [&](float4* wv, float4* av, int kt) {
#pragma unroll
        for (int j = 0; j < 4; j++) {
            wv[j] = *(const float4*)(W1B + kt + j * 4);
            av[j] = *(const float4*)(alB + kt + j * 4);
        }
    };
    auto writeB = [&](const float4* wv, const float4* av, int buf) {
        _Float16* dh = L + buf * 12288 + 4096;
        _Float16* dl = L + buf * 12288 + 8192;
        const float* w = (const float*)wv;
        const float* a = (const float*)av;
        f16x8 h0, l0, h1, l1;
#pragma unroll
        for (int j = 0; j < 8; j++) {
            float p0 = a[j] * w[j];
            _Float16 q0 = (_Float16)p0;
            h0[j] = q0; l0[j] = (_Float16)(p0 - (float)q0);
            float p1 = a[8 + j] * w[8 + j];
            _Float16 q1 = (_Float16)p1;
            h1[j] = q1; l1[j] = (_Float16)(p1 - (float)q1);
        }
        *(f16x8*)(dh + boff + bc0) = h0;
        *(f16x8*)(dh + boff + bc1) = h1;
        *(f16x8*)(dl + boff + bc0) = l0;
        *(f16x8*)(dl + boff + bc1) = l1;
    };

    {   // prologue
        stageA(0, 0);
        float4 wv[4], av[4];
        loadB(wv, av, 0);
        writeB(wv, av, 0);
    }
    __syncthreads();

    int cur = 0;
    for (int kt = 0; kt < H_; kt += 32) {
        const int nxt = cur ^ 1;
        const bool has = (kt + 32) < H_;
        float4 wv[4], av[4];
        if (has) { stageA(nxt, kt + 32); loadB(wv, av, kt + 32); }

        const _Float16* bp = L + cur * 12288;
        f16x8 az[4], bh[4], bl[4];
#pragma unroll
        for (int mi = 0; mi < 4; mi++) {
            int row = wm * 64 + mi * 16 + frow;
            int off = row * 32 + ((fgrp ^ ((row >> 1) & 3)) << 3);
            az[mi] = *(const f16x8*)(bp + off);
        }
#pragma unroll
        for (int ni = 0; ni < 4; ni++) {
            int row = wn * 64 + ni * 16 + frow;
            int off = row * 32 + ((fgrp ^ ((row >> 1) & 3)) << 3);
            bh[ni] = *(const f16x8*)(bp + 4096 + off);
            bl[ni] = *(const f16x8*)(bp + 8192 + off);
        }
#pragma unroll
        for (int mi = 0; mi < 4; mi++)
#pragma unroll
            for (int ni = 0; ni < 4; ni++) {
                acc[mi][ni] = __builtin_amdgcn_mfma_f32_16x16x32_f16(az[mi], bh[ni], acc[mi][ni], 0, 0, 0);
                acc[mi][ni] = __builtin_amdgcn_mfma_f32_16x16x32_f16(az[mi], bl[ni], acc[mi][ni], 0, 0, 0);
            }

        if (has) writeB(wv, av, nxt);
        __syncthreads();
        cur = nxt;
    }

#pragma unroll
    for (int ni = 0; ni < 4; ni++) {
        int col = n0 + wn * 64 + ni * 16 + frow;
        float bv = bW[tt * H_ + col];
#pragma unroll
        for (int mi = 0; mi < 4; mi++) {
            int rbase = r0 + wm * 64 + mi * 16 + fgrp * 4;
#pragma unroll
            for (int p = 0; p < 4; p++)
                C[(size_t)(rbase + p) * H_ + col] = acc[mi][ni][p] + bv;
        }
    }
}

// ---------------------------------------------------------------------------
// bW[t,n] = sum_f beta[t,f]*W1[n,f] + b1[n].  One block per t.
// ---------------------------------------------------------------------------
__global__ __launch_bounds__(512) void bw_kernel(
    const float* __restrict__ beta, const float* __restrict__ W1,
    const float* __restrict__ b1, float* __restrict__ bW)
{
    __shared__ float bs[512];
    const int t = blockIdx.x, n = threadIdx.x;
    bs[n] = beta[t * H_ + n];
    __syncthreads();
    const float* wr = W1 + (size_t)n * H_;
    float s = b1[n];
    for (int f = 0; f < H_; f += 4) {
        float4 w = *(const float4*)(wr + f);
        s = fmaf(bs[f],     w.x, s);
        s = fmaf(bs[f + 1], w.y, s);
        s = fmaf(bs[f + 2], w.z, s);
        s = fmaf(bs[f + 3], w.w, s);
    }
    bW[t * H_ + n] = s;
}

// ---------------------------------------------------------------------------
// LIF scan -> fp16 spikes (0/1 exact). Unfused rounding matches reference.
// ---------------------------------------------------------------------------
__global__ __launch_bounds__(256) void lif_kernel(
    const float* __restrict__ cur, _Float16* __restrict__ z)
{
    const int tid = blockIdx.x * 256 + threadIdx.x;   // b*512 + h
    float v = 0.f, ii = 0.f;
    const float* p = cur + tid;
    _Float16* q = z + tid;
    for (int t = 0; t < T_; t++) {
        float vd = __fadd_rn(v, __fmul_rn(0.1f, __fsub_rn(ii, v)));
        float id = __fmul_rn(ii, 0.95f);
        int zz = (vd > 1.0f) ? 1 : 0;
        v  = zz ? 0.f : vd;
        ii = __fadd_rn(id, p[(size_t)t * BH]);
        q[(size_t)t * BH] = (_Float16)zz;
    }
}

// ---------------------------------------------------------------------------
// BN stats from fp16 spikes: m = sum/512 (exact), var = m - m^2.
// ---------------------------------------------------------------------------
__global__ void bn_kernel(const _Float16* __restrict__ z,
                          const float* __restrict__ g, const float* __restrict__ bt,
                          float* __restrict__ alpha, float* __restrict__ beta)
{
    const int t = blockIdx.x, h = threadIdx.x;
    const _Float16* p = z + (size_t)t * BH + h;
    float fs = 0.f;
    for (int b = 0; b < B_; b++) fs += (float)p[(size_t)b * H_];
    float m   = fs * (1.0f / 512.0f);
    float var = __fsub_rn(m, __fmul_rn(m, m));
    float al  = g[h] / sqrtf(__fadd_rn(var, 1e-5f));
    float be  = __fsub_rn(bt[h], __fmul_rn(m, al));
    alpha[t * H_ + h] = al;
    beta [t * H_ + h] = be;
}

// ---------------------------------------------------------------------------
// U = (alpha1*Z1+beta1) @ Wo^T  — one wave per row.
// ---------------------------------------------------------------------------
__global__ __launch_bounds__(256) void ugemm_kernel(
    const _Float16* __restrict__ Z, const float* __restrict__ alpha,
    const float* __restrict__ beta, const float* __restrict__ Wo,
    float* __restrict__ U)
{
    const int tid  = threadIdx.x;
    const int wave = tid >> 6, lane = tid & 63;
    const size_t r = (size_t)blockIdx.x * 4 + wave;
    const int t = (int)(r >> 9);
    const _Float16* zr = Z + r * 512;
    const float* alp = alpha + t * 512;
    const float* bet = beta  + t * 512;
    float acc[NOUT_];
#pragma unroll
    for (int o = 0; o < NOUT_; o++) acc[o] = 0.f;
#pragma unroll
    for (int jj = 0; jj < 8; jj++) {
        int j = jj * 64 + lane;
        float h = fmaf((float)zr[j], alp[j], bet[j]);
#pragma unroll
        for (int o = 0; o < NOUT_; o++) acc[o] = fmaf(h, Wo[o * 512 + j], acc[o]);
    }
#pragma unroll
    for (int o = 0; o < NOUT_; o++) {
        float v = acc[o];
#pragma unroll
        for (int off = 32; off; off >>= 1) v += __shfl_down(v, off, 64);
        if (lane == 0) U[r * NOUT_ + o] = v;
    }
}

// ---------------------------------------------------------------------------
// Output leaky integrator.
// ---------------------------------------------------------------------------
__global__ void li_kernel(const float* __restrict__ U, float* __restrict__ out)
{
    const int tid = blockIdx.x * 256 + threadIdx.x;   // b*10 + o
    if (tid >= B_ * NOUT_) return;
    float vo = 0.f, io = 0.f;
    for (int t = 0; t < T_; t++) {
        vo = __fadd_rn(vo, __fmul_rn(0.1f, __fsub_rn(io, vo)));
        out[t * (B_ * NOUT_) + tid] = vo;
        io = __fadd_rn(__fmul_rn(io, 0.95f), U[t * (B_ * NOUT_) + tid]);
    }
}

// ---------------------------------------------------------------------------
extern "C" void kernel_launch(void* const* d_in, const int* in_sizes, int n_in,
                              void* d_out, int out_size, void* d_ws, size_t ws_size,
                              hipStream_t stream)
{
    const float* X   = (const float*)d_in[0];
    const float* W0  = (const float*)d_in[1];
    const float* b0  = (const float*)d_in[2];
    const float* W1  = (const float*)d_in[3];
    const float* b1  = (const float*)d_in[4];
    const float* g0  = (const float*)d_in[5];
    const float* bt0 = (const float*)d_in[6];
    const float* g1  = (const float*)d_in[7];
    const float* bt1 = (const float*)d_in[8];
    const float* Wo  = (const float*)d_in[9];
    float* out = (float*)d_out;

    // ws layout (~161 MB): CUR | Zh | alpha0,beta0,alpha1,beta1,bW | U | W0h,W0l
    char* w = (char*)d_ws;
    float*    CUR    = (float*)w;                          // 104,857,600 B
    _Float16* Zh     = (_Float16*)(w + 104857600);         //  52,428,800 B
    float*    alpha0 = (float*)(w + 104857600 + 52428800);
    float*    beta0  = alpha0 + T_*H_;
    float*    alpha1 = beta0  + T_*H_;
    float*    beta1  = alpha1 + T_*H_;
    float*    bW     = beta1  + T_*H_;
    float*    U      = bW     + T_*H_;                     // 2,048,000 B
    _Float16* W0h    = (_Float16*)(U + R_*NOUT_);          // 819,200 B each
    _Float16* W0l    = W0h + 512*FP_;

    convW_kernel<<<(512*FP_+255)/256, 256, 0, stream>>>(W0, W0h, W0l, F_, FP_, 512*FP_);

    gemm0_mfma  <<<1600,  256, 0, stream>>>(X, W0h, W0l, b0, CUR);
    lif_kernel  <<<1024,  256, 0, stream>>>(CUR, Zh);                    // -> Z0
    bn_kernel   <<<100,   512, 0, stream>>>(Zh, g0, bt0, alpha0, beta0);
    bw_kernel   <<<100,   512, 0, stream>>>(beta0, W1, b1, bW);
    gemm1_mfma  <<<1600,  256, 0, stream>>>(Zh, W1, alpha0, bW, CUR);
    lif_kernel  <<<1024,  256, 0, stream>>>(CUR, Zh);                    // -> Z1
    bn_kernel   <<<100,   512, 0, stream>>>(Zh, g1, bt1, alpha1, beta1);
    ugemm_kernel<<<12800, 256, 0, stream>>>(Zh, alpha1, beta1, Wo, U);
    li_kernel   <<<20,    256, 0, stream>>>(U, out);
}

// Round 4
// 590.708 us; speedup vs baseline: 1.9117x; 1.0243x over previous
//
#include <hip/hip_runtime.h>
#include <stdint.h>

#define T_    100
#define B_    512
#define F_    784
#define FP_   800      // K for gemm0, zero-padded to a multiple of 32
#define H_    512
#define NOUT_ 10
#define R_    (T_*B_)      // 51200
#define BH    (B_*H_)      // 262144

typedef _Float16 f16x8 __attribute__((ext_vector_type(8)));
typedef float    f32x4 __attribute__((ext_vector_type(4)));

__device__ __forceinline__ void gload_lds16(const void* g, void* l) {
    __builtin_amdgcn_global_load_lds(
        (const __attribute__((address_space(1))) uint32_t*)g,
        (__attribute__((address_space(3))) uint32_t*)l, 16, 0, 0);
}

// ---------------------------------------------------------------------------
// W0 -> fp16 hi/lo split, zero-padded to Kp columns.
// ---------------------------------------------------------------------------
__global__ void convW_kernel(const float* __restrict__ W, _Float16* __restrict__ Wh,
                             _Float16* __restrict__ Wl, int K, int Kp, int n)
{
    int idx = blockIdx.x * 256 + threadIdx.x;
    if (idx >= n) return;
    int r = idx / Kp, k = idx - r * Kp;
    float v = (k < K) ? W[r * K + k] : 0.f;
    _Float16 h = (_Float16)v;
    Wh[idx] = h;
    Wl[idx] = (_Float16)(v - (float)h);
}

// ---------------------------------------------------------------------------
// GEMM0: CUR[r,n] = sum_k X[r,k]*W0[n,k] + b0[n]   (M=51200,N=512,K=784->800)
// 128x128 tile, BK=32. Counted-vmcnt pipeline: B (gload_lds) 3-deep, A-LDS
// 2-deep, A-regs 2-deep. Raw s_barrier; vmcnt(8) per iter (= drain prev iter's
// 8 vmem ops, keep current iter's 8 in flight). Never vmcnt(0) in main loop.
// ---------------------------------------------------------------------------
__global__ __launch_bounds__(256, 2) void gemm0_mfma(
    const float* __restrict__ X, const _Float16* __restrict__ Wh,
    const _Float16* __restrict__ Wl, const float* __restrict__ bias,
    float* __restrict__ C)
{
    __shared__ _Float16 L[40960];   // A: 2x8192 (Ah|Al), B at 16384: 3x8192 (Bh|Bl)
    const int tid  = threadIdx.x;
    const int gl   = (blockIdx.x & 7) * 200 + (blockIdx.x >> 3);  // 1600 = 8*200
    const int r0   = (gl >> 2) * 128;
    const int n0   = (gl & 3) * 128;
    const int lane = tid & 63;
    const int wm = (tid >> 7) & 1, wn = (tid >> 6) & 1;
    const int frow = lane & 15, fgrp = lane >> 4;

    const int brow = tid >> 2;
    const int bcol = (((tid & 3) ^ ((brow >> 1) & 3)) << 3);
    const _Float16* WhB = Wh + (size_t)(n0 + brow) * FP_ + bcol;
    const _Float16* WlB = Wl + (size_t)(n0 + brow) * FP_ + bcol;

    const int arow = tid >> 1, ahalf = tid & 1;
    const float* Xb = X + (size_t)(r0 + arow) * F_ + ahalf * 16;
    const int aoff = arow * 32;
    const int ac0  = (((ahalf * 2)     ^ ((arow >> 1) & 3)) << 3);
    const int ac1  = (((ahalf * 2 + 1) ^ ((arow >> 1) & 3)) << 3);

    f32x4 acc[4][4];
#pragma unroll
    for (int i = 0; i < 4; i++)
#pragma unroll
        for (int j = 0; j < 4; j++) acc[i][j] = f32x4{0.f, 0.f, 0.f, 0.f};

    auto stageB = [&](int sbuf, int kt) {       // 4 vmem ops
        _Float16* dh = L + 16384 + sbuf * 8192;
        _Float16* dl = dh + 4096;
        gload_lds16(WhB + kt,            dh + tid * 8);
        gload_lds16(WhB + 64 * FP_ + kt, dh + 2048 + tid * 8);
        gload_lds16(WlB + kt,            dl + tid * 8);
        gload_lds16(WlB + 64 * FP_ + kt, dl + 2048 + tid * 8);
    };
    auto loadA = [&](float4 (&xa)[4], int kt) { // 4 vmem ops
#pragma unroll
        for (int j = 0; j < 4; j++) {
            int c = kt + ahalf * 16 + j * 4;
            xa[j] = (c < F_) ? *(const float4*)(Xb + kt + j * 4)
                             : make_float4(0.f, 0.f, 0.f, 0.f);
        }
    };
    auto writeA = [&](int abuf, const float4 (&xa)[4]) {
        _Float16* dh = L + abuf * 8192;
        _Float16* dl = dh + 4096;
        const float* v = (const float*)xa;
        f16x8 h0, l0, h1, l1;
#pragma unroll
        for (int j = 0; j < 8; j++) {
            _Float16 a = (_Float16)v[j];
            h0[j] = a; l0[j] = (_Float16)(v[j] - (float)a);
            _Float16 b = (_Float16)v[8 + j];
            h1[j] = b; l1[j] = (_Float16)(v[8 + j] - (float)b);
        }
        *(f16x8*)(dh + aoff + ac0) = h0;
        *(f16x8*)(dh + aoff + ac1) = h1;
        *(f16x8*)(dl + aoff + ac0) = l0;
        *(f16x8*)(dl + aoff + ac1) = l1;
    };

    float4 R0[4], R1[4];
    // prologue: B tiles 0,1 staged; A tile 0 -> abuf0; A tile 1 in R1
    stageB(0, 0);
    stageB(1, 32);
    loadA(R0, 0);
    loadA(R1, 32);
    writeA(0, R0);
    asm volatile("s_waitcnt lgkmcnt(0)" ::: "memory");
    __builtin_amdgcn_sched_barrier(0);
    __builtin_amdgcn_s_barrier();
    __builtin_amdgcn_sched_barrier(0);

    auto body = [&](int k, int rbuf, int sbuf, float4 (&Rl)[4], float4 (&Rw)[4],
                    bool pf, bool dw) {
        if (pf) { stageB(sbuf, (k + 2) * 32); loadA(Rl, (k + 2) * 32); }
        const _Float16* Ab = L + (k & 1) * 8192;
        const _Float16* Bb = L + 16384 + rbuf * 8192;
        f16x8 ah[4], al[4], bh[4], bl[4];
#pragma unroll
        for (int mi = 0; mi < 4; mi++) {
            int row = wm * 64 + mi * 16 + frow;
            int off = row * 32 + ((fgrp ^ ((row >> 1) & 3)) << 3);
            ah[mi] = *(const f16x8*)(Ab + off);
            al[mi] = *(const f16x8*)(Ab + 4096 + off);
        }
#pragma unroll
        for (int ni = 0; ni < 4; ni++) {
            int row = wn * 64 + ni * 16 + frow;
            int off = row * 32 + ((fgrp ^ ((row >> 1) & 3)) << 3);
            bh[ni] = *(const f16x8*)(Bb + off);
            bl[ni] = *(const f16x8*)(Bb + 4096 + off);
        }
        __builtin_amdgcn_s_setprio(1);
#pragma unroll
        for (int mi = 0; mi < 4; mi++)
#pragma unroll
            for (int ni = 0; ni < 4; ni++) {
                acc[mi][ni] = __builtin_amdgcn_mfma_f32_16x16x32_f16(ah[mi], bh[ni], acc[mi][ni], 0, 0, 0);
                acc[mi][ni] = __builtin_amdgcn_mfma_f32_16x16x32_f16(ah[mi], bl[ni], acc[mi][ni], 0, 0, 0);
                acc[mi][ni] = __builtin_amdgcn_mfma_f32_16x16x32_f16(al[mi], bh[ni], acc[mi][ni], 0, 0, 0);
            }
        __builtin_amdgcn_s_setprio(0);
        if (dw) writeA((k + 1) & 1, Rw);
        asm volatile("s_waitcnt vmcnt(8)" ::: "memory");
        asm volatile("s_waitcnt lgkmcnt(0)" ::: "memory");
        __builtin_amdgcn_sched_barrier(0);
        __builtin_amdgcn_s_barrier();
        __builtin_amdgcn_sched_barrier(0);
    };

    int rb = 0;
    for (int kp = 0; kp < 12; kp++) {
        int k = kp * 2;
        body(k,     rb, rb == 0 ? 2 : rb - 1, R0, R1, (k + 2) <= 24, true);
        rb = (rb == 2) ? 0 : rb + 1;
        body(k + 1, rb, rb == 0 ? 2 : rb - 1, R1, R0, (k + 3) <= 24, true);
        rb = (rb == 2) ? 0 : rb + 1;
    }
    body(24, rb, 0, R0, R1, false, false);

#pragma unroll
    for (int ni = 0; ni < 4; ni++) {
        int col = n0 + wn * 64 + ni * 16 + frow;
        float bv = bias[col];
#pragma unroll
        for (int mi = 0; mi < 4; mi++) {
            int rbase = r0 + wm * 64 + mi * 16 + fgrp * 4;
#pragma unroll
            for (int p = 0; p < 4; p++)
                C[(size_t)(rbase + p) * H_ + col] = acc[mi][ni][p] + bv;
        }
    }
}

// ---------------------------------------------------------------------------
// GEMM1: CUR[r,n] = sum_f Z[r,f] * (alpha[t,f]*W1[n,f]) + bW[t,n]
// A = fp16 spikes (exact) 3-deep gload_lds; B = alpha-folded W1 hi/lo,
// 2-deep reg prefetch. vmcnt(10) per iter (2 stageA + 8 loadB).
// ---------------------------------------------------------------------------
__global__ __launch_bounds__(256, 2) void gemm1_mfma(
    const _Float16* __restrict__ Zh, const float* __restrict__ W1,
    const float* __restrict__ alpha, const float* __restrict__ bW,
    float* __restrict__ C)
{
    __shared__ _Float16 L[28672];   // A: 3x4096; B at 12288: 2x8192 (Bh|Bl)
    const int tid  = threadIdx.x;
    const int gl   = (blockIdx.x & 7) * 200 + (blockIdx.x >> 3);
    const int r0   = (gl >> 2) * 128;
    const int n0   = (gl & 3) * 128;
    const int tt   = r0 >> 9;
    const int lane = tid & 63;
    const int wm = (tid >> 7) & 1, wn = (tid >> 6) & 1;
    const int frow = lane & 15, fgrp = lane >> 4;

    const int arow = tid >> 2;
    const int acol = (((tid & 3) ^ ((arow >> 1) & 3)) << 3);
    const _Float16* ZhB = Zh + (size_t)(r0 + arow) * H_ + acol;

    const int brow = tid >> 1, bhalf = tid & 1;
    const float* W1B = W1 + (size_t)(n0 + brow) * H_ + bhalf * 16;
    const float* alB = alpha + tt * H_ + bhalf * 16;
    const int boff = brow * 32;
    const int bc0  = (((bhalf * 2)     ^ ((brow >> 1) & 3)) << 3);
    const int bc1  = (((bhalf * 2 + 1) ^ ((brow >> 1) & 3)) << 3);

    f32x4 acc[4][4];
#pragma unroll
    for (int i = 0; i < 4; i++)
#pragma unroll
        for (int j = 0; j < 4; j++) acc[i][j] = f32x4{0.f, 0.f, 0.f, 0.f};

    auto stageA = [&](int sbuf, int kt) {       // 2 vmem ops
        _Float16* d = L + sbuf * 4096;
        gload_lds16(ZhB + kt,           d + tid * 8);
        gload_lds16(ZhB + 64 * H_ + kt, d + 2048 + tid * 8);
    };
    auto loadB = [&](float4 (&wv)[4], float4 (&av)[4], int kt) {  // 8 vmem ops
#pragma unroll
        for (int j = 0; j < 4; j++) {
            wv[j] = *(const float4*)(W1B + kt + j * 4);
            av[j] = *(const float4*)(alB + kt + j * 4);
        }
    };
    auto writeB = [&](int wbuf, const float4 (&wv)[4], const float4 (&av)[4]) {
        _Float16* dh = L + 12288 + wbuf * 8192;
        _Float16* dl = dh + 4096;
        const float* w = (const float*)wv;
        const float* a = (const float*)av;
        f16x8 h0, l0, h1, l1;
#pragma unroll
        for (int j = 0; j < 8; j++) {
            float p0 = a[j] * w[j];
            _Float16 q0 = (_Float16)p0;
            h0[j] = q0; l0[j] = (_Float16)(p0 - (float)q0);
            float p1 = a[8 + j] * w[8 + j];
            _Float16 q1 = (_Float16)p1;
            h1[j] = q1; l1[j] = (_Float16)(p1 - (float)q1);
        }
        *(f16x8*)(dh + boff + bc0) = h0;
        *(f16x8*)(dh + boff + bc1) = h1;
        *(f16x8*)(dl + boff + bc0) = l0;
        *(f16x8*)(dl + boff + bc1) = l1;
    };

    float4 Wv0[4], Av0[4], Wv1[4], Av1[4];
    stageA(0, 0);
    stageA(1, 32);
    loadB(Wv0, Av0, 0);
    loadB(Wv1, Av1, 32);
    writeB(0, Wv0, Av0);
    asm volatile("s_waitcnt lgkmcnt(0)" ::: "memory");
    __builtin_amdgcn_sched_barrier(0);
    __builtin_amdgcn_s_barrier();
    __builtin_amdgcn_sched_barrier(0);

    auto body = [&](int k, int rbuf, int sbuf, float4 (&Wl_)[4], float4 (&Al_)[4],
                    float4 (&Ww_)[4], float4 (&Aw_)[4], bool pf, bool dw) {
        if (pf) { stageA(sbuf, (k + 2) * 32); loadB(Wl_, Al_, (k + 2) * 32); }
        const _Float16* Ab = L + rbuf * 4096;
        const _Float16* Bb = L + 12288 + (k & 1) * 8192;
        f16x8 az[4], bh[4], bl[4];
#pragma unroll
        for (int mi = 0; mi < 4; mi++) {
            int row = wm * 64 + mi * 16 + frow;
            int off = row * 32 + ((fgrp ^ ((row >> 1) & 3)) << 3);
            az[mi] = *(const f16x8*)(Ab + off);
        }
#pragma unroll
        for (int ni = 0; ni < 4; ni++) {
            int row = wn * 64 + ni * 16 + frow;
            int off = row * 32 + ((fgrp ^ ((row >> 1) & 3)) << 3);
            bh[ni] = *(const f16x8*)(Bb + off);
            bl[ni] = *(const f16x8*)(Bb + 4096 + off);
        }
        __builtin_amdgcn_s_setprio(1);
#pragma unroll
        for (int mi = 0; mi < 4; mi++)
#pragma unroll
            for (int ni = 0; ni < 4; ni++) {
                acc[mi][ni] = __builtin_amdgcn_mfma_f32_16x16x32_f16(az[mi], bh[ni], acc[mi][ni], 0, 0, 0);
                acc[mi][ni] = __builtin_amdgcn_mfma_f32_16x16x32_f16(az[mi], bl[ni], acc[mi][ni], 0, 0, 0);
            }
        __builtin_amdgcn_s_setprio(0);
        if (dw) writeB((k + 1) & 1, Ww_, Aw_);
        asm volatile("s_waitcnt vmcnt(10)" ::: "memory");
        asm volatile("s_waitcnt lgkmcnt(0)" ::: "memory");
        __builtin_amdgcn_sched_barrier(0);
        __builtin_amdgcn_s_barrier();
        __builtin_amdgcn_sched_barrier(0);
    };

    int rb = 0;
    for (int kp = 0; kp < 7; kp++) {            // k = 0..13, all prefetch
        int k = kp * 2;
        body(k,     rb, rb == 0 ? 2 : rb - 1, Wv0, Av0, Wv1, Av1, true, true);
        rb = (rb == 2) ? 0 : rb + 1;
        body(k + 1, rb, rb == 0 ? 2 : rb - 1, Wv1, Av1, Wv0, Av0, (k + 3) <= 15, true);
        rb = (rb == 2) ? 0 : rb + 1;
    }
    body(14, rb, 0, Wv0, Av0, Wv1, Av1, false, true);   // rb = 2
    rb = 0;
    body(15, rb, 0, Wv1, Av1, Wv0, Av0, false, false);

#pragma unroll
    for (int ni = 0; ni < 4; ni++) {
        int col = n0 + wn * 64 + ni * 16 + frow;
        float bv = bW[tt * H_ + col];
#pragma unroll
        for (int mi = 0; mi < 4; mi++) {
            int rbase = r0 + wm * 64 + mi * 16 + fgrp * 4;
#pragma unroll
            for (int p = 0; p < 4; p++)
                C[(size_t)(rbase + p) * H_ + col] = acc[mi][ni][p] + bv;
        }
    }
}

// ---------------------------------------------------------------------------
// bW[t,n] = sum_f beta[t,f]*W1[n,f] + b1[n].  One block per t.
// ---------------------------------------------------------------------------
__global__ __launch_bounds__(512) void bw_kernel(
    const float* __restrict__ beta, const float* __restrict__ W1,
    const float* __restrict__ b1, float* __restrict__ bW)
{
    __shared__ float bs[512];
    const int t = blockIdx.x, n = threadIdx.x;
    bs[n] = beta[t * H_ + n];
    __syncthreads();
    const float* wr = W1 + (size_t)n * H_;
    float s = b1[n];
    for (int f = 0; f < H_; f += 4) {
        float4 w = *(const float4*)(wr + f);
        s = fmaf(bs[f],     w.x, s);
        s = fmaf(bs[f + 1], w.y, s);
        s = fmaf(bs[f + 2], w.z, s);
        s = fmaf(bs[f + 3], w.w, s);
    }
    bW[t * H_ + n] = s;
}

// ---------------------------------------------------------------------------
// LIF scan -> fp16 spikes (0/1 exact). Unfused rounding matches reference.
// ---------------------------------------------------------------------------
__global__ __launch_bounds__(256) void lif_kernel(
    const float* __restrict__ cur, _Float16* __restrict__ z)
{
    const int tid = blockIdx.x * 256 + threadIdx.x;   // b*512 + h
    float v = 0.f, ii = 0.f;
    const float* p = cur + tid;
    _Float16* q = z + tid;
    for (int t = 0; t < T_; t++) {
        float vd = __fadd_rn(v, __fmul_rn(0.1f, __fsub_rn(ii, v)));
        float id = __fmul_rn(ii, 0.95f);
        int zz = (vd > 1.0f) ? 1 : 0;
        v  = zz ? 0.f : vd;
        ii = __fadd_rn(id, p[(size_t)t * BH]);
        q[(size_t)t * BH] = (_Float16)zz;
    }
}

// ---------------------------------------------------------------------------
// BN stats, two-stage for occupancy. Spike sums are small ints -> exact.
// ---------------------------------------------------------------------------
__global__ __launch_bounds__(512) void bn_part(const _Float16* __restrict__ z,
                                               float* __restrict__ part)
{
    const int t = blockIdx.x >> 3, c = blockIdx.x & 7, h = threadIdx.x;
    const _Float16* p = z + (size_t)t * BH + (size_t)(c * 64) * H_ + h;
    float fs = 0.f;
    for (int b = 0; b < 64; b++) fs += (float)p[(size_t)b * H_];
    part[(size_t)blockIdx.x * H_ + h] = fs;
}

__global__ __launch_bounds__(512) void bn_fin(const float* __restrict__ part,
                          const float* __restrict__ g, const float* __restrict__ bt,
                          float* __restrict__ alpha, float* __restrict__ beta)
{
    const int t = blockIdx.x, h = threadIdx.x;
    float fs = 0.f;
#pragma unroll
    for (int c = 0; c < 8; c++) fs += part[(size_t)(t * 8 + c) * H_ + h];
    float m   = fs * (1.0f / 512.0f);
    float var = __fsub_rn(m, __fmul_rn(m, m));
    float al  = g[h] / sqrtf(__fadd_rn(var, 1e-5f));
    float be  = __fsub_rn(bt[h], __fmul_rn(m, al));
    alpha[t * H_ + h] = al;
    beta [t * H_ + h] = be;
}

// ---------------------------------------------------------------------------
// U = (alpha1*Z1+beta1) @ Wo^T  — one wave per row.
// ---------------------------------------------------------------------------
__global__ __launch_bounds__(256) void ugemm_kernel(
    const _Float16* __restrict__ Z, const float* __restrict__ alpha,
    const float* __restrict__ beta, const float* __restrict__ Wo,
    float* __restrict__ U)
{
    const int tid  = threadIdx.x;
    const int wave = tid >> 6, lane = tid & 63;
    const size_t r = (size_t)blockIdx.x * 4 + wave;
    const int t = (int)(r >> 9);
    const _Float16* zr = Z + r * 512;
    const float* alp = alpha + t * 512;
    const float* bet = beta  + t * 512;
    float acc[NOUT_];
#pragma unroll
    for (int o = 0; o < NOUT_; o++) acc[o] = 0.f;
#pragma unroll
    for (int jj = 0; jj < 8; jj++) {
        int j = jj * 64 + lane;
        float h = fmaf((float)zr[j], alp[j], bet[j]);
#pragma unroll
        for (int o = 0; o < NOUT_; o++) acc[o] = fmaf(h, Wo[o * 512 + j], acc[o]);
    }
#pragma unroll
    for (int o = 0; o < NOUT_; o++) {
        float v = acc[o];
#pragma unroll
        for (int off = 32; off; off >>= 1) v += __shfl_down(v, off, 64);
        if (lane == 0) U[r * NOUT_ + o] = v;
    }
}

// ---------------------------------------------------------------------------
// Output leaky integrator.
// ---------------------------------------------------------------------------
__global__ void li_kernel(const float* __restrict__ U, float* __restrict__ out)
{
    const int tid = blockIdx.x * 256 + threadIdx.x;   // b*10 + o
    if (tid >= B_ * NOUT_) return;
    float vo = 0.f, io = 0.f;
    for (int t = 0; t < T_; t++) {
        vo = __fadd_rn(vo, __fmul_rn(0.1f, __fsub_rn(io, vo)));
        out[t * (B_ * NOUT_) + tid] = vo;
        io = __fadd_rn(__fmul_rn(io, 0.95f), U[t * (B_ * NOUT_) + tid]);
    }
}

// ---------------------------------------------------------------------------
extern "C" void kernel_launch(void* const* d_in, const int* in_sizes, int n_in,
                              void* d_out, int out_size, void* d_ws, size_t ws_size,
                              hipStream_t stream)
{
    const float* X   = (const float*)d_in[0];
    const float* W0  = (const float*)d_in[1];
    const float* b0  = (const float*)d_in[2];
    const float* W1  = (const float*)d_in[3];
    const float* b1  = (const float*)d_in[4];
    const float* g0  = (const float*)d_in[5];
    const float* bt0 = (const float*)d_in[6];
    const float* g1  = (const float*)d_in[7];
    const float* bt1 = (const float*)d_in[8];
    const float* Wo  = (const float*)d_in[9];
    float* out = (float*)d_out;

    // ws layout (~164 MB): CUR | Zh | alpha0,beta0,alpha1,beta1,bW | U | W0h,W0l | part
    char* w = (char*)d_ws;
    float*    CUR    = (float*)w;                          // 104,857,600 B
    _Float16* Zh     = (_Float16*)(w + 104857600);         //  52,428,800 B
    float*    alpha0 = (float*)(w + 104857600 + 52428800);
    float*    beta0  = alpha0 + T_*H_;
    float*    alpha1 = beta0  + T_*H_;
    float*    beta1  = alpha1 + T_*H_;
    float*    bW     = beta1  + T_*H_;
    float*    U      = bW     + T_*H_;                     // 2,048,000 B
    _Float16* W0h    = (_Float16*)(U + R_*NOUT_);          // 819,200 B each
    _Float16* W0l    = W0h + 512*FP_;
    float*    part   = (float*)(W0l + 512*FP_);            // 1,638,400 B

    convW_kernel<<<(512*FP_+255)/256, 256, 0, stream>>>(W0, W0h, W0l, F_, FP_, 512*FP_);

    gemm0_mfma  <<<1600,  256, 0, stream>>>(X, W0h, W0l, b0, CUR);
    lif_kernel  <<<1024,  256, 0, stream>>>(CUR, Zh);                    // -> Z0
    bn_part     <<<800,   512, 0, stream>>>(Zh, part);
    bn_fin      <<<100,   512, 0, stream>>>(part, g0, bt0, alpha0, beta0);
    bw_kernel   <<<100,   512, 0, stream>>>(beta0, W1, b1, bW);
    gemm1_mfma  <<<1600,  256, 0, stream>>>(Zh, W1, alpha0, bW, CUR);
    lif_kernel  <<<1024,  256, 0, stream>>>(CUR, Zh);                    // -> Z1
    bn_part     <<<800,   512, 0, stream>>>(Zh, part);
    bn_fin      <<<100,   512, 0, stream>>>(part, g1, bt1, alpha1, beta1);
    ugemm_kernel<<<12800, 256, 0, stream>>>(Zh, alpha1, beta1, Wo, U);
    li_kernel   <<<20,    256, 0, stream>>>(U, out);
}